// Round 4
// baseline (344.544 us; speedup 1.0000x reference)
//
#include <hip/hip_runtime.h>

#define N_   8
#define C_   256
#define H_   128
#define W_   128
#define HW_  16384
#define NB_  20
constexpr float TEMP  = 0.5f;
constexpr float IMG_W = 800.0f;
constexpr float IMG_H = 800.0f;

typedef float f32x4 __attribute__((ext_vector_type(4)));   // native vector for nt builtins

// ---------------------------------------------------------------------------
// K1: single pass over preds_T (134 MB). Regular (caching) loads on purpose:
// we WANT pT resident in L3 for k_main's second read.
//   fea_sum[n*HW+hw]            = sum_c |pT[hw,n,c]|
//   chan_part[(n*64+p)*C + c]   = block-partial sum_hw |pT[hw,n,c]|  (no atomics)
// grid 512 x 256: block -> n = bid&7, p = bid>>3; wave handles 64 rows.
// ---------------------------------------------------------------------------
__global__ __launch_bounds__(256) void k_stats(const float* __restrict__ pT,
                                               float* __restrict__ chan_part,
                                               float* __restrict__ fea_sum) {
    const int n    = blockIdx.x & 7;
    const int p    = blockIdx.x >> 3;
    const int wave = threadIdx.x >> 6;
    const int lane = threadIdx.x & 63;
    __shared__ float rowp[4][64 * 65];   // [wave][row*65 + lane], +1 pad
    __shared__ float chl[4][C_];

    float4 cacc = make_float4(0.f, 0.f, 0.f, 0.f);
    const int hw0 = p * 256 + wave * 64;
    const float* base = pT + ((size_t)(hw0 * N_ + n)) * C_ + lane * 4;
    #pragma unroll 8
    for (int i = 0; i < 64; ++i) {
        const float4 v = *(const float4*)(base + (size_t)i * (N_ * C_));
        const float ax = fabsf(v.x), ay = fabsf(v.y), az = fabsf(v.z), aw = fabsf(v.w);
        cacc.x += ax; cacc.y += ay; cacc.z += az; cacc.w += aw;
        rowp[wave][i * 65 + lane] = ax + ay + az + aw;
    }
    chl[wave][lane * 4 + 0] = cacc.x;
    chl[wave][lane * 4 + 1] = cacc.y;
    chl[wave][lane * 4 + 2] = cacc.z;
    chl[wave][lane * 4 + 3] = cacc.w;
    __syncthreads();
    // transpose reduce: thread t -> (wave w_=t>>6, row r=t&63)
    {
        const int w_ = threadIdx.x >> 6, r = threadIdx.x & 63;
        float s = 0.f;
        #pragma unroll
        for (int j = 0; j < 64; ++j) s += rowp[w_][r * 65 + j];
        fea_sum[n * HW_ + p * 256 + threadIdx.x] = s;   // coalesced
    }
    const int c = threadIdx.x;
    chan_part[((size_t)(n * 64 + p)) * C_ + c] =
        chl[0][c] + chl[1][c] + chl[2][c] + chl[3][c];
}

// ---------------------------------------------------------------------------
// K2: fused per-image kernel. grid 8 x 256, block owns image n entirely:
//   reduce chan_part -> channel softmax -> B[n,c]=sqrt(C_att);
//   spatial softmax stats; box masks (LDS), bg count; A[n,hw].
// ---------------------------------------------------------------------------
__global__ __launch_bounds__(256) void k_perN(const float* __restrict__ fea_sum,
                                              const float* __restrict__ chan_part,
                                              const float* __restrict__ gt,
                                              float* __restrict__ A,
                                              float* __restrict__ B) {
    const int n = blockIdx.x;
    const int tid = threadIdx.x;
    __shared__ float red[256];
    __shared__ int   bh0[NB_], bh1[NB_], bw0[NB_], bw1[NB_];
    __shared__ float barea[NB_];
    __shared__ float MfgL[HW_];          // 64 KB
    __shared__ float sc[1];

    if (tid < NB_) {
        const float* bx = gt + ((size_t)n * NB_ + tid) * 4;
        const float wminf = floorf(bx[0] / IMG_W * (float)W_);
        const float wmaxf = ceilf (bx[2] / IMG_W * (float)W_);
        const float hminf = floorf(bx[1] / IMG_H * (float)H_);
        const float hmaxf = ceilf (bx[3] / IMG_H * (float)H_);
        bw0[tid] = (int)wminf; bw1[tid] = (int)wmaxf;
        bh0[tid] = (int)hminf; bh1[tid] = (int)hmaxf;
        barea[tid] = 1.0f / (hmaxf + 1.0f - hminf) / (wmaxf + 1.0f - wminf);
    }

    // ---- reduce channel partials (64 blocks worth) then channel softmax
    float csum = 0.f;
    for (int p = 0; p < 64; ++p)
        csum += chan_part[((size_t)(n * 64 + p)) * C_ + tid];
    const float lc = csum * (1.0f / (HW_ * TEMP));
    red[tid] = lc; __syncthreads();
    for (int s = 128; s > 0; s >>= 1) { if (tid < s) red[tid] = fmaxf(red[tid], red[tid + s]); __syncthreads(); }
    const float cmax = red[0]; __syncthreads();
    const float e = expf(lc - cmax);
    red[tid] = e; __syncthreads();
    for (int s = 128; s > 0; s >>= 1) { if (tid < s) red[tid] += red[tid + s]; __syncthreads(); }
    if (tid == 0) sc[0] = red[0];
    __syncthreads();
    B[n * C_ + tid] = sqrtf((float)C_ * e / sc[0]);

    // ---- spatial softmax stats over fea_sum[n, :]
    __syncthreads();
    float m = -1e30f;
    for (int i = tid; i < HW_; i += 256) m = fmaxf(m, fea_sum[n * HW_ + i]);
    red[tid] = m; __syncthreads();
    for (int s = 128; s > 0; s >>= 1) { if (tid < s) red[tid] = fmaxf(red[tid], red[tid + s]); __syncthreads(); }
    const float smax = red[0] * (1.0f / (C_ * TEMP));
    __syncthreads();
    float acc = 0.f;
    for (int i = tid; i < HW_; i += 256)
        acc += expf(fea_sum[n * HW_ + i] * (1.0f / (C_ * TEMP)) - smax);
    red[tid] = acc; __syncthreads();
    for (int s = 128; s > 0; s >>= 1) { if (tid < s) red[tid] += red[tid + s]; __syncthreads(); }
    const float sden = red[0];
    __syncthreads();

    // ---- foreground mask + bg count (w fixed per thread -> w-mask once)
    const int w = tid & 127;
    unsigned wmask = 0;
    for (int b = 0; b < NB_; ++b)
        if (w >= bw0[b] && w <= bw1[b]) wmask |= (1u << b);
    float cnt = 0.f;
    for (int k = 0; k < HW_ / 256; ++k) {
        const int i = tid + k * 256;
        const int h = i >> 7;
        float fg = 0.f;
        for (int b = 0; b < NB_; ++b)
            if (((wmask >> b) & 1u) && h >= bh0[b] && h <= bh1[b]) fg = fmaxf(fg, barea[b]);
        MfgL[i] = fg;
        cnt += (fg <= 0.f) ? 1.f : 0.f;
    }
    red[tid] = cnt; __syncthreads();
    for (int s = 128; s > 0; s >>= 1) { if (tid < s) red[tid] += red[tid + s]; __syncthreads(); }
    const float bgsum = red[0];
    const float bgval = (bgsum > 0.f) ? 1.0f / bgsum : 1.0f;

    // ---- A[n,hw]
    for (int k = 0; k < HW_ / 256; ++k) {
        const int i = tid + k * 256;
        const float fg = MfgL[i];
        const float S_att = (float)HW_ *
            expf(fea_sum[n * HW_ + i] * (1.0f / (C_ * TEMP)) - smax) / sden;
        const float bgv = (fg <= 0.f) ? bgval : 0.f;
        A[n * HW_ + i] = sqrtf(S_att) * (sqrtf(fg) + sqrtf(bgv)) * (1.0f / (float)HW_);
    }
}

// ---------------------------------------------------------------------------
// K3: main weighted-L1 reduction. pT read with normal (caching) loads — it
// should be L3-resident from k_stats. pS read NONTEMPORAL (native vector) so
// it does not evict pT from L3 -> HBM fetch ~134 MB instead of ~268 MB.
// grid 1024 x 256 = 4096 waves; wave -> n = wg&7, 32 consecutive hw rows.
// ---------------------------------------------------------------------------
__device__ __forceinline__ float waveReduceSum(float v) {
    v += __shfl_xor(v, 32, 64);
    v += __shfl_xor(v, 16, 64);
    v += __shfl_xor(v, 8, 64);
    v += __shfl_xor(v, 4, 64);
    v += __shfl_xor(v, 2, 64);
    v += __shfl_xor(v, 1, 64);
    return v;
}

__global__ __launch_bounds__(256) void k_main(const float* __restrict__ pS,
                                              const float* __restrict__ pT,
                                              const float* __restrict__ A,
                                              const float* __restrict__ B,
                                              float* __restrict__ partials) {
    const int wave = threadIdx.x >> 6, lane = threadIdx.x & 63;
    const int wg = blockIdx.x * 4 + wave;      // 0..4095
    const int n = wg & 7;
    const int widx = wg >> 3;                  // 0..511
    const float4 B4 = *(const float4*)(B + n * C_ + lane * 4);
    float acc = 0.f;
    const int hw0 = widx * 32;
    #pragma unroll 4
    for (int i = 0; i < 32; ++i) {
        const int hw = hw0 + i;
        const size_t off = ((size_t)(hw * N_ + n)) * C_ + lane * 4;
        const float4 tv = *(const float4*)(pT + off);                        // L3 hit (hot from k_stats)
        const f32x4  sv = __builtin_nontemporal_load((const f32x4*)(pS + off)); // nt: don't pollute L3
        const float part = fabsf(sv.x - tv.x) * B4.x + fabsf(sv.y - tv.y) * B4.y +
                           fabsf(sv.z - tv.z) * B4.z + fabsf(sv.w - tv.w) * B4.w;
        acc += A[n * HW_ + hw] * part;
    }
    acc = waveReduceSum(acc);
    __shared__ float red[4];
    if (lane == 0) red[wave] = acc;
    __syncthreads();
    if (threadIdx.x == 0) partials[blockIdx.x] = red[0] + red[1] + red[2] + red[3];
}

__global__ __launch_bounds__(256) void k_final(const float* __restrict__ partials,
                                               float* __restrict__ out) {
    float a = 0.f;
    for (int i = threadIdx.x; i < 1024; i += 256) a += partials[i];
    __shared__ float red[256];
    red[threadIdx.x] = a; __syncthreads();
    for (int s = 128; s > 0; s >>= 1) { if (threadIdx.x < s) red[threadIdx.x] += red[threadIdx.x + s]; __syncthreads(); }
    if (threadIdx.x == 0) out[0] = red[0];
}

extern "C" void kernel_launch(void* const* d_in, const int* in_sizes, int n_in,
                              void* d_out, int out_size, void* d_ws, size_t ws_size,
                              hipStream_t stream) {
    const float* pS = (const float*)d_in[0];
    const float* pT = (const float*)d_in[1];
    const float* gt = (const float*)d_in[2];
    float* ws = (float*)d_ws;

    // workspace layout (floats) — everything fully written before read; no memset
    float* chan_part = ws;                        // 8*64*256 = 131072
    float* fea_sum   = ws + 131072;               // 131072
    float* A         = fea_sum + N_ * HW_;        // 131072
    float* B         = A + N_ * HW_;              // 2048
    float* partials  = B + N_ * C_;               // 1024

    k_stats<<<512, 256, 0, stream>>>(pT, chan_part, fea_sum);
    k_perN<<<N_, 256, 0, stream>>>(fea_sum, chan_part, gt, A, B);
    k_main<<<1024, 256, 0, stream>>>(pS, pT, A, B, partials);
    k_final<<<1, 256, 0, stream>>>(partials, (float*)d_out);
}

// Round 5
// 344.139 us; speedup vs baseline: 1.0012x; 1.0012x over previous
//
#include <hip/hip_runtime.h>

#define N_   8
#define C_   256
#define H_   128
#define W_   128
#define HW_  16384
#define NB_  20
constexpr float TEMP  = 0.5f;
constexpr float IMG_W = 800.0f;
constexpr float IMG_H = 800.0f;

typedef float    f32x4 __attribute__((ext_vector_type(4)));
typedef _Float16 f16x4 __attribute__((ext_vector_type(4)));

// ---------------------------------------------------------------------------
// K1: ONE pass over preds_T AND preds_S (268 MB, nontemporal — never re-read).
//   fea_sum[n*HW+hw]          = sum_c |pT[hw,n,c]|
//   chan_part[(n*64+p)*C + c] = block-partial sum_hw |pT[hw,n,c]|
//   D[hw,n,c]                 = (fp16) |pS - pT|     (cached stores -> L3)
// grid 512 x 256: block -> n = bid&7, p = bid>>3; wave handles 64 rows.
// ---------------------------------------------------------------------------
__global__ __launch_bounds__(256) void k_statsD(const float* __restrict__ pS,
                                                const float* __restrict__ pT,
                                                _Float16* __restrict__ D,
                                                float* __restrict__ chan_part,
                                                float* __restrict__ fea_sum) {
    const int n    = blockIdx.x & 7;
    const int p    = blockIdx.x >> 3;
    const int wave = threadIdx.x >> 6;
    const int lane = threadIdx.x & 63;
    __shared__ float rowp[4][64 * 65];   // [wave][row*65 + lane], +1 pad
    __shared__ float chl[4][C_];

    float4 cacc = make_float4(0.f, 0.f, 0.f, 0.f);
    const int hw0 = p * 256 + wave * 64;
    const size_t base = ((size_t)(hw0 * N_ + n)) * C_ + lane * 4;
    #pragma unroll 4
    for (int i = 0; i < 64; ++i) {
        const size_t off = base + (size_t)i * (N_ * C_);
        const f32x4 tv = __builtin_nontemporal_load((const f32x4*)(pT + off));
        const f32x4 sv = __builtin_nontemporal_load((const f32x4*)(pS + off));
        const float ax = fabsf(tv.x), ay = fabsf(tv.y), az = fabsf(tv.z), aw = fabsf(tv.w);
        cacc.x += ax; cacc.y += ay; cacc.z += az; cacc.w += aw;
        rowp[wave][i * 65 + lane] = ax + ay + az + aw;
        f16x4 d;
        d.x = (_Float16)fabsf(sv.x - tv.x);
        d.y = (_Float16)fabsf(sv.y - tv.y);
        d.z = (_Float16)fabsf(sv.z - tv.z);
        d.w = (_Float16)fabsf(sv.w - tv.w);
        *(f16x4*)(D + off) = d;          // regular store: want L3 residency
    }
    chl[wave][lane * 4 + 0] = cacc.x;
    chl[wave][lane * 4 + 1] = cacc.y;
    chl[wave][lane * 4 + 2] = cacc.z;
    chl[wave][lane * 4 + 3] = cacc.w;
    __syncthreads();
    // transpose reduce: thread t -> (wave w_=t>>6, row r=t&63)
    {
        const int w_ = threadIdx.x >> 6, r = threadIdx.x & 63;
        float s = 0.f;
        #pragma unroll
        for (int j = 0; j < 64; ++j) s += rowp[w_][r * 65 + j];
        fea_sum[n * HW_ + p * 256 + threadIdx.x] = s;   // coalesced
    }
    const int c = threadIdx.x;
    chan_part[((size_t)(n * 64 + p)) * C_ + c] =
        chl[0][c] + chl[1][c] + chl[2][c] + chl[3][c];
}

// ---------------------------------------------------------------------------
// K2: fused per-image kernel. grid 8 x 256, block owns image n entirely:
//   reduce chan_part -> channel softmax -> B[n,c]=sqrt(C_att);
//   spatial softmax stats; box masks (LDS), bg count; A[n,hw].
// ---------------------------------------------------------------------------
__global__ __launch_bounds__(256) void k_perN(const float* __restrict__ fea_sum,
                                              const float* __restrict__ chan_part,
                                              const float* __restrict__ gt,
                                              float* __restrict__ A,
                                              float* __restrict__ B) {
    const int n = blockIdx.x;
    const int tid = threadIdx.x;
    __shared__ float red[256];
    __shared__ int   bh0[NB_], bh1[NB_], bw0[NB_], bw1[NB_];
    __shared__ float barea[NB_];
    __shared__ float MfgL[HW_];          // 64 KB
    __shared__ float sc[1];

    if (tid < NB_) {
        const float* bx = gt + ((size_t)n * NB_ + tid) * 4;
        const float wminf = floorf(bx[0] / IMG_W * (float)W_);
        const float wmaxf = ceilf (bx[2] / IMG_W * (float)W_);
        const float hminf = floorf(bx[1] / IMG_H * (float)H_);
        const float hmaxf = ceilf (bx[3] / IMG_H * (float)H_);
        bw0[tid] = (int)wminf; bw1[tid] = (int)wmaxf;
        bh0[tid] = (int)hminf; bh1[tid] = (int)hmaxf;
        barea[tid] = 1.0f / (hmaxf + 1.0f - hminf) / (wmaxf + 1.0f - wminf);
    }

    // ---- reduce channel partials (64 blocks worth) then channel softmax
    float csum = 0.f;
    for (int p = 0; p < 64; ++p)
        csum += chan_part[((size_t)(n * 64 + p)) * C_ + tid];
    const float lc = csum * (1.0f / (HW_ * TEMP));
    red[tid] = lc; __syncthreads();
    for (int s = 128; s > 0; s >>= 1) { if (tid < s) red[tid] = fmaxf(red[tid], red[tid + s]); __syncthreads(); }
    const float cmax = red[0]; __syncthreads();
    const float e = expf(lc - cmax);
    red[tid] = e; __syncthreads();
    for (int s = 128; s > 0; s >>= 1) { if (tid < s) red[tid] += red[tid + s]; __syncthreads(); }
    if (tid == 0) sc[0] = red[0];
    __syncthreads();
    B[n * C_ + tid] = sqrtf((float)C_ * e / sc[0]);

    // ---- spatial softmax stats over fea_sum[n, :]
    __syncthreads();
    float m = -1e30f;
    for (int i = tid; i < HW_; i += 256) m = fmaxf(m, fea_sum[n * HW_ + i]);
    red[tid] = m; __syncthreads();
    for (int s = 128; s > 0; s >>= 1) { if (tid < s) red[tid] = fmaxf(red[tid], red[tid + s]); __syncthreads(); }
    const float smax = red[0] * (1.0f / (C_ * TEMP));
    __syncthreads();
    float acc = 0.f;
    for (int i = tid; i < HW_; i += 256)
        acc += expf(fea_sum[n * HW_ + i] * (1.0f / (C_ * TEMP)) - smax);
    red[tid] = acc; __syncthreads();
    for (int s = 128; s > 0; s >>= 1) { if (tid < s) red[tid] += red[tid + s]; __syncthreads(); }
    const float sden = red[0];
    __syncthreads();

    // ---- foreground mask + bg count (w fixed per thread -> w-mask once)
    const int w = tid & 127;
    unsigned wmask = 0;
    for (int b = 0; b < NB_; ++b)
        if (w >= bw0[b] && w <= bw1[b]) wmask |= (1u << b);
    float cnt = 0.f;
    for (int k = 0; k < HW_ / 256; ++k) {
        const int i = tid + k * 256;
        const int h = i >> 7;
        float fg = 0.f;
        for (int b = 0; b < NB_; ++b)
            if (((wmask >> b) & 1u) && h >= bh0[b] && h <= bh1[b]) fg = fmaxf(fg, barea[b]);
        MfgL[i] = fg;
        cnt += (fg <= 0.f) ? 1.f : 0.f;
    }
    red[tid] = cnt; __syncthreads();
    for (int s = 128; s > 0; s >>= 1) { if (tid < s) red[tid] += red[tid + s]; __syncthreads(); }
    const float bgsum = red[0];
    const float bgval = (bgsum > 0.f) ? 1.0f / bgsum : 1.0f;

    // ---- A[n,hw]
    for (int k = 0; k < HW_ / 256; ++k) {
        const int i = tid + k * 256;
        const float fg = MfgL[i];
        const float S_att = (float)HW_ *
            expf(fea_sum[n * HW_ + i] * (1.0f / (C_ * TEMP)) - smax) / sden;
        const float bgv = (fg <= 0.f) ? bgval : 0.f;
        A[n * HW_ + i] = sqrtf(S_att) * (sqrtf(fg) + sqrtf(bgv)) * (1.0f / (float)HW_);
    }
}

// ---------------------------------------------------------------------------
// K3: reduce D (fp16, 67 MB, expected L3-hot) with weights A (per row) and
// B (per channel). grid 1024 x 256 = 4096 waves; wave -> n = wg&7, 32 rows;
// lane owns c = lane*4..+3 (8 B loads).
// ---------------------------------------------------------------------------
__device__ __forceinline__ float waveReduceSum(float v) {
    v += __shfl_xor(v, 32, 64);
    v += __shfl_xor(v, 16, 64);
    v += __shfl_xor(v, 8, 64);
    v += __shfl_xor(v, 4, 64);
    v += __shfl_xor(v, 2, 64);
    v += __shfl_xor(v, 1, 64);
    return v;
}

__global__ __launch_bounds__(256) void k_red(const _Float16* __restrict__ D,
                                             const float* __restrict__ A,
                                             const float* __restrict__ B,
                                             float* __restrict__ partials) {
    const int wave = threadIdx.x >> 6, lane = threadIdx.x & 63;
    const int wg = blockIdx.x * 4 + wave;      // 0..4095
    const int n = wg & 7;
    const int widx = wg >> 3;                  // 0..511
    const float4 B4 = *(const float4*)(B + n * C_ + lane * 4);
    float acc = 0.f;
    const int hw0 = widx * 32;
    #pragma unroll 8
    for (int i = 0; i < 32; ++i) {
        const int hw = hw0 + i;
        const size_t off = ((size_t)(hw * N_ + n)) * C_ + lane * 4;
        const f16x4 dv = *(const f16x4*)(D + off);
        const float part = (float)dv.x * B4.x + (float)dv.y * B4.y +
                           (float)dv.z * B4.z + (float)dv.w * B4.w;
        acc += A[n * HW_ + hw] * part;
    }
    acc = waveReduceSum(acc);
    __shared__ float red[4];
    if (lane == 0) red[wave] = acc;
    __syncthreads();
    if (threadIdx.x == 0) partials[blockIdx.x] = red[0] + red[1] + red[2] + red[3];
}

__global__ __launch_bounds__(256) void k_final(const float* __restrict__ partials,
                                               float* __restrict__ out) {
    float a = 0.f;
    for (int i = threadIdx.x; i < 1024; i += 256) a += partials[i];
    __shared__ float red[256];
    red[threadIdx.x] = a; __syncthreads();
    for (int s = 128; s > 0; s >>= 1) { if (threadIdx.x < s) red[threadIdx.x] += red[threadIdx.x + s]; __syncthreads(); }
    if (threadIdx.x == 0) out[0] = red[0];
}

extern "C" void kernel_launch(void* const* d_in, const int* in_sizes, int n_in,
                              void* d_out, int out_size, void* d_ws, size_t ws_size,
                              hipStream_t stream) {
    const float* pS = (const float*)d_in[0];
    const float* pT = (const float*)d_in[1];
    const float* gt = (const float*)d_in[2];
    float* ws = (float*)d_ws;

    // workspace layout (floats) — everything fully written before read; no memset
    float*    chan_part = ws;                     // 8*64*256 = 131072
    float*    fea_sum   = ws + 131072;            // 131072
    float*    A         = fea_sum + N_ * HW_;     // 131072
    float*    B         = A + N_ * HW_;           // 2048
    float*    partials  = B + N_ * C_;            // 1024
    _Float16* D         = (_Float16*)(partials + 1024);  // 33.5M halves = 67 MB

    k_statsD<<<512, 256, 0, stream>>>(pS, pT, D, chan_part, fea_sum);
    k_perN<<<N_, 256, 0, stream>>>(fea_sum, chan_part, gt, A, B);
    k_red<<<1024, 256, 0, stream>>>(D, A, B, partials);
    k_final<<<1, 256, 0, stream>>>(partials, (float*)d_out);
}